// Round 2
// baseline (11745.934 us; speedup 1.0000x reference)
//
#include <hip/hip_runtime.h>
#include <cstddef>

#define LD 33
#define WLD 35
#define GLD 65
#define IDX(r,c) ((r)*LD+(c))
#define WIDX(r,c) ((r)*WLD+(c))
#define GIDX(r,c) ((r)*GLD+(c))
#define EPS_TRI 0.01f
#define EPS_BS 1e-4f

// ---------------- Phase 1: Ris[t] = Ri[t] Ri[t]^T, Rm[t] = Ris[t] ms[t] ----------------
__global__ __launch_bounds__(256) void ris_kernel(const float* __restrict__ Ri,
                                                  const float* __restrict__ ms,
                                                  float* __restrict__ Ris,
                                                  float* __restrict__ Rm) {
  const int t = blockIdx.x;
  const int tid = threadIdx.x;
  __shared__ float sR[32*LD];
  __shared__ float sRis[32*LD];
  __shared__ float sm[32];
  {
    const int e = tid * 4;
    const int r = e >> 5, c = e & 31;
    const float4 v = *(const float4*)(Ri + (size_t)t*1024 + e);
    sR[IDX(r,c)+0] = v.x; sR[IDX(r,c)+1] = v.y; sR[IDX(r,c)+2] = v.z; sR[IDX(r,c)+3] = v.w;
    if (tid < 32) sm[tid] = ms[t*32 + tid];
  }
  __syncthreads();
  const int r = tid >> 3, c0 = (tid & 7) * 4;
  float a0=0.f,a1=0.f,a2=0.f,a3=0.f;
#pragma unroll
  for (int p = 0; p < 32; p++) {
    const float rr = sR[IDX(r,p)];
    a0 += rr * sR[IDX(c0+0,p)];
    a1 += rr * sR[IDX(c0+1,p)];
    a2 += rr * sR[IDX(c0+2,p)];
    a3 += rr * sR[IDX(c0+3,p)];
  }
  sRis[IDX(r,c0+0)] = a0; sRis[IDX(r,c0+1)] = a1;
  sRis[IDX(r,c0+2)] = a2; sRis[IDX(r,c0+3)] = a3;
  float4 o; o.x=a0; o.y=a1; o.z=a2; o.w=a3;
  *(float4*)(Ris + (size_t)t*1024 + r*32 + c0) = o;
  __syncthreads();
  if (tid < 32) {
    float acc = 0.f;
#pragma unroll
    for (int j = 0; j < 32; j++) acc += sRis[IDX(tid,j)] * sm[j];
    Rm[t*32 + tid] = acc;
  }
}

// ---------------- Phase 2: per-sample sequential chain (one block per sample) ----------------
// Sampling path (matches reference chol scan exactly):
//   M_k = Jd_k - Ll_{k-1} Ll_{k-1}^T + eps*I, L = chol(M), W = L^{-1}, Ll_k = Jl_k W,
//   x_k = (L+1e-4 I)^{-T}(z_k - Ll_{k-1}^T x_{k-1}).
// Fwd path (matches reference fwd scan exactly, ASYMMETRIC):
//   J_k = Jd_k - Jl_{k-1} c_{k-1} + eps*I  (= Jd + P_prev c_prev + eps, Jl=-P)
//   c_k = Jl_k J_k^{-T},  d_k = J_k^{-1} (h_k - Jl_{k-1} d_{k-1})
//   J^{-1} via no-pivot Gauss-Jordan: [J|I] -> [diag(p)|B], J^{-1}[i][j] = B[i][j]/p_i.
__global__ __launch_bounds__(256) void fwd_kernel(const float* __restrict__ z,
                                                  const float* __restrict__ A_base,
                                                  const float* __restrict__ b_base,
                                                  const float* __restrict__ Q_sqrt,
                                                  const float* __restrict__ noise,
                                                  const float* __restrict__ Ris,
                                                  const float* __restrict__ Rm,
                                                  float* __restrict__ c_ws,
                                                  float* __restrict__ d_ws,
                                                  float* __restrict__ x_ws) {
  const int bn = blockIdx.x;       // sample index
  const int tid = threadIdx.x;
  const int r  = tid >> 3;         // row 0..31
  const int g  = tid & 7;          // col group 0..7
  const int c0 = g * 4;            // 4 consecutive cols per thread

  __shared__ float sAs[32*LD], sQs[32*LD], sM[32*LD], sL[32*LD];
  __shared__ float sQis[2][32*LD], sP[2][32*LD], sLl[2][32*LD], sC[2][32*LD];
  __shared__ float sW[32*WLD];
  __shared__ float sGJ[32*GLD];
  __shared__ float sz[2048];
  __shared__ float s_bs[32], s_rhs[32], s_d[32], s_x[32], s_xr[32];
  __shared__ float s_inv[32], s_invr[32], s_invp[32], s_hc[2][32];

  // preload this sample's z row (T*K = 2048 floats)
  {
    const float* zn = z + (size_t)bn * 2048;
    const int e = tid * 8;
    float4 v0 = *(const float4*)(zn + e);
    float4 v1 = *(const float4*)(zn + e + 4);
    *(float4*)(sz + e)     = v0;
    *(float4*)(sz + e + 4) = v1;
  }
  __syncthreads();

  for (int k = 0; k < 256; k++) {
    const int cur = k & 1, prv = cur ^ 1;
    const bool have_cur = (k < 255);
    const bool have_prv = (k >= 1);

    // ---- Stage A: mix As = sum z_q A_q, Qs = sum z_q Q_q, bs = sum z_q b_q ----
    if (have_cur) {
      float a0=0.f,a1=0.f,a2=0.f,a3=0.f,q0=0.f,q1=0.f,q2=0.f,q3=0.f;
#pragma unroll
      for (int kq = 0; kq < 8; kq++) {
        const float zq = sz[k*8 + kq];
        const float4 av = *(const float4*)(A_base + kq*1024 + r*32 + c0);
        const float4 qv = *(const float4*)(Q_sqrt + kq*1024 + r*32 + c0);
        a0 += zq*av.x; a1 += zq*av.y; a2 += zq*av.z; a3 += zq*av.w;
        q0 += zq*qv.x; q1 += zq*qv.y; q2 += zq*qv.z; q3 += zq*qv.w;
      }
      sAs[IDX(r,c0+0)]=a0; sAs[IDX(r,c0+1)]=a1; sAs[IDX(r,c0+2)]=a2; sAs[IDX(r,c0+3)]=a3;
      sQs[IDX(r,c0+0)]=q0; sQs[IDX(r,c0+1)]=q1; sQs[IDX(r,c0+2)]=q2; sQs[IDX(r,c0+3)]=q3;
      if (tid < 32) {
        float b = 0.f;
#pragma unroll
        for (int kq = 0; kq < 8; kq++) b += sz[k*8+kq] * b_base[kq*32 + tid];
        s_bs[tid] = b;
      }
    }
    __syncthreads();

    // ---- Stage B: Qis = Qs Qs^T ----
    if (have_cur) {
      float a0=0.f,a1=0.f,a2=0.f,a3=0.f;
#pragma unroll
      for (int p = 0; p < 32; p++) {
        const float qr = sQs[IDX(r,p)];
        a0 += qr * sQs[IDX(c0+0,p)];
        a1 += qr * sQs[IDX(c0+1,p)];
        a2 += qr * sQs[IDX(c0+2,p)];
        a3 += qr * sQs[IDX(c0+3,p)];
      }
      sQis[cur][IDX(r,c0+0)]=a0; sQis[cur][IDX(r,c0+1)]=a1;
      sQis[cur][IDX(r,c0+2)]=a2; sQis[cur][IDX(r,c0+3)]=a3;
    }
    __syncthreads();

    // ---- Stage C: P = Qis * As   (Jl = -P) ----
    if (have_cur) {
      float a0=0.f,a1=0.f,a2=0.f,a3=0.f;
#pragma unroll
      for (int p = 0; p < 32; p++) {
        const float qr = sQis[cur][IDX(r,p)];
        a0 += qr * sAs[IDX(p,c0+0)];
        a1 += qr * sAs[IDX(p,c0+1)];
        a2 += qr * sAs[IDX(p,c0+2)];
        a3 += qr * sAs[IDX(p,c0+3)];
      }
      sP[cur][IDX(r,c0+0)]=a0; sP[cur][IDX(r,c0+1)]=a1;
      sP[cur][IDX(r,c0+2)]=a2; sP[cur][IDX(r,c0+3)]=a3;
    }
    __syncthreads();

    // ---- Stage D: base = Jd + eps I; sM = base - Ll_prv Ll_prv^T; sJ = base + P_prv c_prv.
    //      Also vectors: rhs, hcarry, x-rhs. ----
    {
      const float4 rv = *(const float4*)(Ris + (size_t)k*1024 + r*32 + c0);
      float b0 = rv.x, b1 = rv.y, b2 = rv.z, b3 = rv.w;
      if (r == c0+0) b0 += EPS_TRI;
      else if (r == c0+1) b1 += EPS_TRI;
      else if (r == c0+2) b2 += EPS_TRI;
      else if (r == c0+3) b3 += EPS_TRI;
      if (have_cur) {
#pragma unroll
        for (int p = 0; p < 32; p++) {
          const float ar = sAs[IDX(p,r)];
          b0 += ar * sP[cur][IDX(p,c0+0)];
          b1 += ar * sP[cur][IDX(p,c0+1)];
          b2 += ar * sP[cur][IDX(p,c0+2)];
          b3 += ar * sP[cur][IDX(p,c0+3)];
        }
      }
      float m0=b0, m1=b1, m2=b2, m3=b3;
      float j0=b0, j1=b1, j2=b2, j3=b3;
      if (have_prv) {
        const float q0 = sQis[prv][IDX(r,c0+0)];
        const float q1 = sQis[prv][IDX(r,c0+1)];
        const float q2 = sQis[prv][IDX(r,c0+2)];
        const float q3 = sQis[prv][IDX(r,c0+3)];
        m0 += q0; m1 += q1; m2 += q2; m3 += q3;
        j0 += q0; j1 += q1; j2 += q2; j3 += q3;
#pragma unroll
        for (int p = 0; p < 32; p++) {
          const float lr = sLl[prv][IDX(r,p)];
          m0 -= lr * sLl[prv][IDX(c0+0,p)];
          m1 -= lr * sLl[prv][IDX(c0+1,p)];
          m2 -= lr * sLl[prv][IDX(c0+2,p)];
          m3 -= lr * sLl[prv][IDX(c0+3,p)];
          const float pr = sP[prv][IDX(r,p)];
          j0 += pr * sC[prv][IDX(p,c0+0)];
          j1 += pr * sC[prv][IDX(p,c0+1)];
          j2 += pr * sC[prv][IDX(p,c0+2)];
          j3 += pr * sC[prv][IDX(p,c0+3)];
        }
      }
      sM[IDX(r,c0+0)]=m0; sM[IDX(r,c0+1)]=m1; sM[IDX(r,c0+2)]=m2; sM[IDX(r,c0+3)]=m3;
      sGJ[GIDX(r,c0+0)]=j0; sGJ[GIDX(r,c0+1)]=j1; sGJ[GIDX(r,c0+2)]=j2; sGJ[GIDX(r,c0+3)]=j3;
      sGJ[GIDX(r,32+c0+0)] = (r == c0+0) ? 1.f : 0.f;
      sGJ[GIDX(r,32+c0+1)] = (r == c0+1) ? 1.f : 0.f;
      sGJ[GIDX(r,32+c0+2)] = (r == c0+2) ? 1.f : 0.f;
      sGJ[GIDX(r,32+c0+3)] = (r == c0+3) ? 1.f : 0.f;

      if (tid < 32) {
        const int i = tid;
        float h = Rm[k*32 + i];
        if (have_cur) {
          float a = 0.f;
#pragma unroll
          for (int j = 0; j < 32; j++) a += sP[cur][IDX(i,j)] * s_bs[j];
          h -= a;                     // Jl*bs = -P*bs
        }
        if (have_prv) h += s_hc[prv][i];
        float rr2 = h;
        if (have_prv) {
          float a = 0.f;
#pragma unroll
          for (int j = 0; j < 32; j++) a += sP[prv][IDX(i,j)] * s_d[j];
          rr2 += a;                   // -Jl_prev d_prev = +P_prev d_prev
        }
        s_rhs[i] = rr2;
      } else if (tid < 64) {
        const int i = tid - 32;
        if (have_cur) {
          float a = 0.f;
#pragma unroll
          for (int j = 0; j < 32; j++) a += sQis[cur][IDX(i,j)] * s_bs[j];
          s_hc[cur][i] = a;           // Qis[k] bs[k], consumed at k+1
        }
      } else if (tid < 96) {
        const int i = tid - 64;
        float xr = noise[(size_t)bn*8192 + k*32 + i];
        if (have_prv) {
          float a = 0.f;
#pragma unroll
          for (int j = 0; j < 32; j++) a += sLl[prv][IDX(j,i)] * s_x[j];
          xr -= a;                    // z_k - Ll_prev^T x_prev
        }
        s_xr[i] = xr;
      }
    }
    __syncthreads();

    // ---- Stage E: fused Cholesky(sM->sL) + Gauss-Jordan(sGJ). 1 barrier per column. ----
    for (int j = 0; j < 32; j++) {
      // Cholesky on sM
      {
        const float dj = sM[IDX(j,j)];
        const float sq = sqrtf(dj);
        const float inv = 1.0f / sq;
        const float mrj = sM[IDX(r,j)] * inv;
        if (g == 0 && r >= j) sL[IDX(r,j)] = (r == j) ? sq : mrj;
        if (r > j) {
#pragma unroll
          for (int i2 = 0; i2 < 4; i2++) {
            const int c = c0 + i2;
            if (c > j && c <= r) sM[IDX(r,c)] -= mrj * (sM[IDX(c,j)] * inv);
          }
        }
      }
      // Gauss-Jordan on sGJ (no pivoting; no row-normalize; skip left cols <= j)
      {
        const float pj = sGJ[GIDX(j,j)];
        const float ip = 1.0f / pj;
        if (r == j && g == 0) s_invp[j] = ip;
        if (r != j) {
          const float f = sGJ[GIDX(r,j)] * ip;
#pragma unroll
          for (int i2 = 0; i2 < 4; i2++) {
            const int c = c0 + i2;
            if (c > j) sGJ[GIDX(r,c)] -= f * sGJ[GIDX(j,c)];
          }
#pragma unroll
          for (int i2 = 0; i2 < 4; i2++) {
            const int c = 32 + c0 + i2;
            sGJ[GIDX(r,c)] -= f * sGJ[GIDX(j,c)];
          }
        }
      }
      __syncthreads();
    }

    // ---- diag reciprocals + W init ----
    if (tid < 32) {
      const float l = sL[IDX(tid,tid)];
      s_inv[tid]  = 1.0f / l;
      s_invr[tid] = 1.0f / (l + EPS_BS);
    }
#pragma unroll
    for (int i2 = 0; i2 < 4; i2++) sW[WIDX(r,c0+i2)] = 0.f;
    __syncthreads();

    // ---- Stage W: W = L^{-1}, column-parallel (8 lanes per column, wave-sync) ----
    {
      const int col = r;
      if (g == 0) sW[WIDX(col,col)] = s_inv[col];
      for (int i = 1; i < 32; i++) {
        float t = 0.f;
        for (int p = g; p < i; p += 8) t += sL[IDX(i,p)] * sW[WIDX(p,col)];
        t += __shfl_xor(t, 1);
        t += __shfl_xor(t, 2);
        t += __shfl_xor(t, 4);
        if (g == 0 && i > col) sW[WIDX(i,col)] = -t * s_inv[i];
      }
    }
    __syncthreads();

    // ---- Final stage: Ll = -P W; c = -invp .* (P B^T) (store + keep); d; x back-substitution ----
    if (have_cur) {
      float l0=0.f,l1=0.f,l2=0.f,l3=0.f;
      float v0=0.f,v1=0.f,v2=0.f,v3=0.f;
#pragma unroll
      for (int p = 0; p < 32; p++) {
        const float pr = sP[cur][IDX(r,p)];
        l0 += pr * sW[WIDX(p,c0+0)];
        l1 += pr * sW[WIDX(p,c0+1)];
        l2 += pr * sW[WIDX(p,c0+2)];
        l3 += pr * sW[WIDX(p,c0+3)];
        v0 += pr * sGJ[GIDX(c0+0,32+p)];
        v1 += pr * sGJ[GIDX(c0+1,32+p)];
        v2 += pr * sGJ[GIDX(c0+2,32+p)];
        v3 += pr * sGJ[GIDX(c0+3,32+p)];
      }
      sLl[cur][IDX(r,c0+0)]=-l0; sLl[cur][IDX(r,c0+1)]=-l1;
      sLl[cur][IDX(r,c0+2)]=-l2; sLl[cur][IDX(r,c0+3)]=-l3;
      v0 *= -s_invp[c0+0]; v1 *= -s_invp[c0+1];
      v2 *= -s_invp[c0+2]; v3 *= -s_invp[c0+3];
      sC[cur][IDX(r,c0+0)]=v0; sC[cur][IDX(r,c0+1)]=v1;
      sC[cur][IDX(r,c0+2)]=v2; sC[cur][IDX(r,c0+3)]=v3;
      float4 cv; cv.x=v0; cv.y=v1; cv.z=v2; cv.w=v3;
      *(float4*)(c_ws + ((size_t)(bn*255 + k))*1024 + r*32 + c0) = cv;
    }
    if (tid < 32) {
      // d = J^{-1} rhs = invp .* (B rhs)
      float acc = 0.f;
#pragma unroll
      for (int j = 0; j < 32; j++) acc += sGJ[GIDX(tid,32+j)] * s_rhs[j];
      acc *= s_invp[tid];
      s_d[tid] = acc;
      d_ws[((size_t)(bn*256 + k))*32 + tid] = acc;
    } else if (tid >= 64 && tid < 96) {
      const int i = tid - 64;      // lanes 0..31 of wave 1
      float xr = s_xr[i];
      float xv = 0.f;
      for (int j = 31; j >= 0; j--) {
        const float t = __shfl(xr, j, 32) * s_invr[j];
        if (i == j) xv = t;
        else if (i < j) xr -= sL[IDX(j,i)] * t;
      }
      s_x[i] = xv;
      x_ws[((size_t)(bn*256 + k))*32 + i] = xv;
    }
    __syncthreads();
  }
}

// ---------------- Phase 3: backward mu scan + output = x + mu ----------------
__global__ __launch_bounds__(256) void bwd_kernel(const float* __restrict__ c_ws,
                                                  const float* __restrict__ d_ws,
                                                  const float* __restrict__ x_ws,
                                                  float* __restrict__ out) {
  const int bn = blockIdx.x;
  const int tid = threadIdx.x;
  const int i = tid >> 3, g = tid & 7;
  __shared__ float s_mu[32];
  if (tid < 32) {
    const float mu = d_ws[((size_t)(bn*256 + 255))*32 + tid];
    s_mu[tid] = mu;
    out[((size_t)(bn*256 + 255))*32 + tid] =
        x_ws[((size_t)(bn*256 + 255))*32 + tid] + mu;
  }
  __syncthreads();
  float4 cv = *(const float4*)(c_ws + ((size_t)(bn*255 + 254))*1024 + i*32 + g*4);
  for (int k = 254; k >= 0; k--) {
    float4 cnext = make_float4(0.f, 0.f, 0.f, 0.f);
    if (k > 0)
      cnext = *(const float4*)(c_ws + ((size_t)(bn*255 + k - 1))*1024 + i*32 + g*4);
    float part = cv.x * s_mu[g*4+0] + cv.y * s_mu[g*4+1]
               + cv.z * s_mu[g*4+2] + cv.w * s_mu[g*4+3];
    part += __shfl_xor(part, 1);
    part += __shfl_xor(part, 2);
    part += __shfl_xor(part, 4);
    float dv = 0.f, xv = 0.f;
    if (g == 0) {
      dv = d_ws[((size_t)(bn*256 + k))*32 + i];
      xv = x_ws[((size_t)(bn*256 + k))*32 + i];
    }
    __syncthreads();   // all reads of s_mu done
    if (g == 0) {
      const float mu = dv - part;
      s_mu[i] = mu;
      out[((size_t)(bn*256 + k))*32 + i] = xv + mu;
    }
    __syncthreads();
    cv = cnext;
  }
}

extern "C" void kernel_launch(void* const* d_in, const int* in_sizes, int n_in,
                              void* d_out, int out_size, void* d_ws, size_t ws_size,
                              hipStream_t stream) {
  const float* z      = (const float*)d_in[0];   // (64,256,8)
  const float* A_base = (const float*)d_in[1];   // (8,32,32)
  const float* b_base = (const float*)d_in[2];   // (8,32)
  const float* Q_sqrt = (const float*)d_in[3];   // (8,32,32)
  const float* ms     = (const float*)d_in[4];   // (256,32)
  const float* Ri     = (const float*)d_in[5];   // (256,32,32)
  const float* noise  = (const float*)d_in[6];   // (64,8192)
  float* out = (float*)d_out;

  float* ws = (float*)d_ws;
  // ws layout (floats): c (64*255*1024) | d (64*256*32) | x (64*256*32) | Ris (256*1024) | Rm (256*32)
  float* c_ws  = ws;
  float* d_vec = c_ws + (size_t)64*255*1024;
  float* x_vec = d_vec + (size_t)64*256*32;
  float* Ris   = x_vec + (size_t)64*256*32;
  float* Rm    = Ris + (size_t)256*1024;

  ris_kernel<<<256, 256, 0, stream>>>(Ri, ms, Ris, Rm);
  fwd_kernel<<<64, 256, 0, stream>>>(z, A_base, b_base, Q_sqrt, noise, Ris, Rm,
                                     c_ws, d_vec, x_vec);
  bwd_kernel<<<64, 256, 0, stream>>>(c_ws, d_vec, x_vec, out);
}

// Round 3
// 4147.636 us; speedup vs baseline: 2.8320x; 2.8320x over previous
//
#include <hip/hip_runtime.h>
#include <cstddef>

#define LD 33
#define WLD 35
#define GLD 65
#define IDX(r,c) ((r)*LD+(c))
#define WIDX(r,c) ((r)*WLD+(c))
#define GIDX(r,c) ((r)*GLD+(c))
#define EPS_TRI 0.01f
#define EPS_BS 1e-4f
#define F4C(v,e) ((e)==0?(v).x:(e)==1?(v).y:(e)==2?(v).z:(v).w)

// ---------------- Phase 1: Ris[t] = Ri[t] Ri[t]^T, Rm[t] = Ris[t] ms[t] ----------------
__global__ __launch_bounds__(256) void ris_kernel(const float* __restrict__ Ri,
                                                  const float* __restrict__ ms,
                                                  float* __restrict__ Ris,
                                                  float* __restrict__ Rm) {
  const int t = blockIdx.x;
  const int tid = threadIdx.x;
  __shared__ float sR[32*LD];
  __shared__ float sRis[32*LD];
  __shared__ float sm[32];
  {
    const int e = tid * 4;
    const int r = e >> 5, c = e & 31;
    const float4 v = *(const float4*)(Ri + (size_t)t*1024 + e);
    sR[IDX(r,c)+0] = v.x; sR[IDX(r,c)+1] = v.y; sR[IDX(r,c)+2] = v.z; sR[IDX(r,c)+3] = v.w;
    if (tid < 32) sm[tid] = ms[t*32 + tid];
  }
  __syncthreads();
  const int r = tid >> 3, c0 = (tid & 7) * 4;
  float a0=0.f,a1=0.f,a2=0.f,a3=0.f;
#pragma unroll
  for (int p = 0; p < 32; p++) {
    const float rr = sR[IDX(r,p)];
    a0 += rr * sR[IDX(c0+0,p)];
    a1 += rr * sR[IDX(c0+1,p)];
    a2 += rr * sR[IDX(c0+2,p)];
    a3 += rr * sR[IDX(c0+3,p)];
  }
  sRis[IDX(r,c0+0)] = a0; sRis[IDX(r,c0+1)] = a1;
  sRis[IDX(r,c0+2)] = a2; sRis[IDX(r,c0+3)] = a3;
  float4 o; o.x=a0; o.y=a1; o.z=a2; o.w=a3;
  *(float4*)(Ris + (size_t)t*1024 + r*32 + c0) = o;
  __syncthreads();
  if (tid < 32) {
    float acc = 0.f;
#pragma unroll
    for (int j = 0; j < 32; j++) acc += sRis[IDX(tid,j)] * sm[j];
    Rm[t*32 + tid] = acc;
  }
}

// ---------------- Phase 2 (new): parallel precompute of Jdbase, P, h per (n,t) ----------------
// Jdb[n][t] = Ris[t] + eps*I + As_t^T P_t (t<255) + Qis_{t-1} (t>=1)
// P[n][t]   = Qis_t As_t (t<255)
// h[n][t]   = Rm[t] - P_t bs_t (t<255) + Qis_{t-1} bs_{t-1} (t>=1)
__global__ __launch_bounds__(256) void pre_kernel(
    const float* __restrict__ z, const float* __restrict__ A_base,
    const float* __restrict__ b_base, const float* __restrict__ Q_sqrt,
    const float* __restrict__ Ris, const float* __restrict__ Rm,
    float* __restrict__ Jdb, float* __restrict__ Pm, float* __restrict__ h_ws) {
  const int n = blockIdx.x >> 8;
  const int t = blockIdx.x & 255;
  const int tid = threadIdx.x;
  const int r = tid >> 3, c0 = (tid & 7) * 4;
  const bool hcv = (t < 255);
  const bool hpv = (t >= 1);
  __shared__ __align__(16) float sAs[32*LD], sQs[32*LD], sQsp[32*LD];
  __shared__ __align__(16) float sQis[32*LD], sQisp[32*LD], sP[32*LD];
  __shared__ float s_z[16];
  __shared__ float s_bs[32], s_bsp[32];
  if (tid < 8)       s_z[tid] = hcv ? z[((size_t)n << 11) + t*8 + tid] : 0.f;
  else if (tid < 16) s_z[tid] = hpv ? z[((size_t)n << 11) + (t-1)*8 + (tid-8)] : 0.f;
  __syncthreads();
  {
    float a0=0,a1=0,a2=0,a3=0,q0=0,q1=0,q2=0,q3=0,p0=0,p1=0,p2=0,p3=0;
#pragma unroll
    for (int kq = 0; kq < 8; kq++) {
      const float zc = s_z[kq], zp = s_z[8+kq];
      const float4 av = *(const float4*)(A_base + kq*1024 + r*32 + c0);
      const float4 qv = *(const float4*)(Q_sqrt + kq*1024 + r*32 + c0);
      a0 += zc*av.x; a1 += zc*av.y; a2 += zc*av.z; a3 += zc*av.w;
      q0 += zc*qv.x; q1 += zc*qv.y; q2 += zc*qv.z; q3 += zc*qv.w;
      p0 += zp*qv.x; p1 += zp*qv.y; p2 += zp*qv.z; p3 += zp*qv.w;
    }
    sAs[IDX(r,c0+0)]=a0; sAs[IDX(r,c0+1)]=a1; sAs[IDX(r,c0+2)]=a2; sAs[IDX(r,c0+3)]=a3;
    sQs[IDX(r,c0+0)]=q0; sQs[IDX(r,c0+1)]=q1; sQs[IDX(r,c0+2)]=q2; sQs[IDX(r,c0+3)]=q3;
    sQsp[IDX(r,c0+0)]=p0; sQsp[IDX(r,c0+1)]=p1; sQsp[IDX(r,c0+2)]=p2; sQsp[IDX(r,c0+3)]=p3;
    if (tid < 32) {
      float b = 0.f;
#pragma unroll
      for (int kq = 0; kq < 8; kq++) b += s_z[kq] * b_base[kq*32 + tid];
      s_bs[tid] = b;
    } else if (tid < 64) {
      const int i = tid - 32;
      float b = 0.f;
#pragma unroll
      for (int kq = 0; kq < 8; kq++) b += s_z[8+kq] * b_base[kq*32 + i];
      s_bsp[i] = b;
    }
  }
  __syncthreads();
  {
    float a0=0,a1=0,a2=0,a3=0,b0=0,b1=0,b2=0,b3=0;
#pragma unroll
    for (int p = 0; p < 32; p++) {
      const float qr = sQs[IDX(r,p)];
      a0 += qr * sQs[IDX(c0+0,p)];
      a1 += qr * sQs[IDX(c0+1,p)];
      a2 += qr * sQs[IDX(c0+2,p)];
      a3 += qr * sQs[IDX(c0+3,p)];
      const float pr2 = sQsp[IDX(r,p)];
      b0 += pr2 * sQsp[IDX(c0+0,p)];
      b1 += pr2 * sQsp[IDX(c0+1,p)];
      b2 += pr2 * sQsp[IDX(c0+2,p)];
      b3 += pr2 * sQsp[IDX(c0+3,p)];
    }
    sQis[IDX(r,c0+0)]=a0; sQis[IDX(r,c0+1)]=a1; sQis[IDX(r,c0+2)]=a2; sQis[IDX(r,c0+3)]=a3;
    sQisp[IDX(r,c0+0)]=b0; sQisp[IDX(r,c0+1)]=b1; sQisp[IDX(r,c0+2)]=b2; sQisp[IDX(r,c0+3)]=b3;
  }
  __syncthreads();
  {
    float a0=0,a1=0,a2=0,a3=0;
#pragma unroll
    for (int p = 0; p < 32; p++) {
      const float qr = sQis[IDX(r,p)];
      a0 += qr * sAs[IDX(p,c0+0)];
      a1 += qr * sAs[IDX(p,c0+1)];
      a2 += qr * sAs[IDX(p,c0+2)];
      a3 += qr * sAs[IDX(p,c0+3)];
    }
    sP[IDX(r,c0+0)]=a0; sP[IDX(r,c0+1)]=a1; sP[IDX(r,c0+2)]=a2; sP[IDX(r,c0+3)]=a3;
    if (hcv) {
      float4 v; v.x=a0; v.y=a1; v.z=a2; v.w=a3;
      *(float4*)(Pm + ((size_t)(n*255 + t))*1024 + r*32 + c0) = v;
    }
  }
  __syncthreads();
  {
    const float4 rv = *(const float4*)(Ris + (size_t)t*1024 + r*32 + c0);
    float j0 = rv.x, j1 = rv.y, j2 = rv.z, j3 = rv.w;
    if (r == c0+0) j0 += EPS_TRI;
    else if (r == c0+1) j1 += EPS_TRI;
    else if (r == c0+2) j2 += EPS_TRI;
    else if (r == c0+3) j3 += EPS_TRI;
    if (hcv) {
#pragma unroll
      for (int p = 0; p < 32; p++) {
        const float ar = sAs[IDX(p,r)];
        j0 += ar * sP[IDX(p,c0+0)];
        j1 += ar * sP[IDX(p,c0+1)];
        j2 += ar * sP[IDX(p,c0+2)];
        j3 += ar * sP[IDX(p,c0+3)];
      }
    }
    if (hpv) {
      j0 += sQisp[IDX(r,c0+0)];
      j1 += sQisp[IDX(r,c0+1)];
      j2 += sQisp[IDX(r,c0+2)];
      j3 += sQisp[IDX(r,c0+3)];
    }
    float4 v; v.x=j0; v.y=j1; v.z=j2; v.w=j3;
    *(float4*)(Jdb + ((size_t)(n*256 + t))*1024 + r*32 + c0) = v;
    if (tid < 32) {
      float h = Rm[t*32 + tid];
      if (hcv) {
        float a = 0.f;
#pragma unroll
        for (int j = 0; j < 32; j++) a += sP[IDX(tid,j)] * s_bs[j];
        h -= a;
      }
      if (hpv) {
        float a = 0.f;
#pragma unroll
        for (int j = 0; j < 32; j++) a += sQisp[IDX(tid,j)] * s_bsp[j];
        h += a;
      }
      h_ws[((size_t)(n*256 + t))*32 + tid] = h;
    }
  }
}

// ---------------- Phase 3 (new): two independent single-wave sequential chains ----------------
// role 0 (blocks 0..63):   GJ chain -> c, d      role 1 (blocks 64..127): chol chain -> x
__global__ __launch_bounds__(64) void chain_kernel(
    const float* __restrict__ Jdb, const float* __restrict__ Pm,
    const float* __restrict__ h_ws, const float* __restrict__ noise,
    float* __restrict__ c_ws, float* __restrict__ d_ws, float* __restrict__ x_ws) {
  const int bn   = blockIdx.x & 63;
  const int role = blockIdx.x >> 6;
  const int lane = threadIdx.x;
  const int r    = lane >> 1;
  const int h2   = lane & 1;
  const int c16  = h2 * 16;

  const float* Jb = Jdb + (size_t)bn * 256 * 1024;
  const float* Pb = Pm  + (size_t)bn * 255 * 1024;

  if (role == 0) {
    // ================== GJ chain: J_k = Jdb_k + P_{k-1} c_{k-1}; no-pivot Gauss-Jordan ==================
    __shared__ __align__(16) float sP[2][32*36];
    __shared__ __align__(16) float sCT[32*36];   // c_prev transposed
    __shared__ __align__(16) float sB[32*36];    // GJ right half rows
    __shared__ __align__(16) float s_rhs[32];
    __shared__ __align__(16) float s_d[32];
    __shared__ __align__(16) float s_invp[32];
    const float* hb = h_ws + (size_t)bn * 256 * 32;

    float4 jq[4], pq[4]; float hq;
#pragma unroll
    for (int q = 0; q < 4; q++) jq[q] = *(const float4*)(Jb + r*32 + c16 + 4*q);
#pragma unroll
    for (int q = 0; q < 4; q++) pq[q] = *(const float4*)(Pb + r*32 + c16 + 4*q);
    hq = hb[r];

    for (int k = 0; k < 256; k++) {
      const int cur = k & 1, prv = cur ^ 1;
      if (k < 255) {
#pragma unroll
        for (int q = 0; q < 4; q++) *(float4*)(&sP[cur][r*36 + c16 + 4*q]) = pq[q];
      }
      __syncthreads();
      // prefetch k+1
      float4 jn[4], pn[4]; float hn = 0.f;
      if (k < 255) {
#pragma unroll
        for (int q = 0; q < 4; q++)
          jn[q] = *(const float4*)(Jb + (size_t)(k+1)*1024 + r*32 + c16 + 4*q);
        hn = hb[(k+1)*32 + r];
        if (k + 1 < 255) {
#pragma unroll
          for (int q = 0; q < 4; q++)
            pn[q] = *(const float4*)(Pb + (size_t)(k+1)*1024 + r*32 + c16 + 4*q);
        }
      }
      // rhs_k = h_k + P_{k-1} d_{k-1}
      float rhs_r = hq;
      if (k >= 1) {
        float a = 0.f;
#pragma unroll
        for (int q = 0; q < 8; q++) {
          const float4 pv = *(const float4*)(&sP[prv][r*36 + 4*q]);
          const float4 dv = *(const float4*)(&s_d[4*q]);
          a += pv.x*dv.x + pv.y*dv.y + pv.z*dv.z + pv.w*dv.w;
        }
        rhs_r += a;
      }
      if (h2 == 0) s_rhs[r] = rhs_r;
      // J build: tmp = Jdb row slice + P_prev row · cT rows
      float tmp[16];
#pragma unroll
      for (int i = 0; i < 16; i++) tmp[i] = F4C(jq[i >> 2], i & 3);
      if (k >= 1) {
        float prow[32];
#pragma unroll
        for (int q = 0; q < 8; q++) {
          const float4 v = *(const float4*)(&sP[prv][r*36 + 4*q]);
          prow[4*q]=v.x; prow[4*q+1]=v.y; prow[4*q+2]=v.z; prow[4*q+3]=v.w;
        }
#pragma unroll
        for (int i = 0; i < 16; i++) {
          const int c = c16 + i;
          float acc = 0.f;
#pragma unroll
          for (int q = 0; q < 8; q++) {
            const float4 v = *(const float4*)(&sCT[c*36 + 4*q]);
            acc += prow[4*q]*v.x + prow[4*q+1]*v.y + prow[4*q+2]*v.z + prow[4*q+3]*v.w;
          }
          tmp[i] += acc;
        }
      }
      // register layout: left lane holds J row r (cols 0..31), right lane holds B row r (cols 32..63)
      float g[32];
      if (h2 == 1) {
#pragma unroll
        for (int i = 0; i < 32; i++) g[i] = (i == r) ? 1.f : 0.f;
      }
#pragma unroll
      for (int i = 0; i < 16; i++) {
        const float oth = __shfl_xor(tmp[i], 1);
        if (h2 == 0) { g[i] = tmp[i]; g[16+i] = oth; }
      }
      // Gauss-Jordan, fully in registers, pivot-row broadcast via bpermute
      float my_piv = 1.f;
#pragma unroll
      for (int j = 0; j < 32; j++) {
        float pr_[32];
#pragma unroll
        for (int i = 0; i < 32; i++) pr_[i] = __shfl(g[i], 2*j + h2);
        const float dpiv = __shfl(g[j], 2*j);
        const float ip = __builtin_amdgcn_rcpf(dpiv);
        float f = __shfl(g[j], 2*r) * ip;
        if (j == r) { my_piv = dpiv; f = 0.f; }
#pragma unroll
        for (int i = 0; i < 32; i++) g[i] -= f * pr_[i];
      }
      const float ipv = __builtin_amdgcn_rcpf(my_piv);
      if (h2 == 0) s_invp[r] = ipv;
      else {
#pragma unroll
        for (int q = 0; q < 8; q++) {
          float4 v; v.x=g[4*q]; v.y=g[4*q+1]; v.z=g[4*q+2]; v.w=g[4*q+3];
          *(float4*)(&sB[r*36 + 4*q]) = v;
        }
      }
      __syncthreads();
      // d_k = invp .* (B rhs)
      if (h2 == 1) {
        float acc = 0.f;
#pragma unroll
        for (int q = 0; q < 8; q++) {
          const float4 rv = *(const float4*)(&s_rhs[4*q]);
          acc += g[4*q]*rv.x + g[4*q+1]*rv.y + g[4*q+2]*rv.z + g[4*q+3]*rv.w;
        }
        const float dv = acc * ipv;
        s_d[r] = dv;
        d_ws[((size_t)(bn*256 + k))*32 + r] = dv;
      }
      // c_k = -(P_k B^T) col-scaled by invp
      if (k < 255) {
        float prow[32];
#pragma unroll
        for (int q = 0; q < 8; q++) {
          const float4 v = *(const float4*)(&sP[cur][r*36 + 4*q]);
          prow[4*q]=v.x; prow[4*q+1]=v.y; prow[4*q+2]=v.z; prow[4*q+3]=v.w;
        }
        float outv[16];
#pragma unroll
        for (int i = 0; i < 16; i++) {
          const int c = c16 + i;
          float acc = 0.f;
#pragma unroll
          for (int q = 0; q < 8; q++) {
            const float4 v = *(const float4*)(&sB[c*36 + 4*q]);
            acc += prow[4*q]*v.x + prow[4*q+1]*v.y + prow[4*q+2]*v.z + prow[4*q+3]*v.w;
          }
          outv[i] = -acc * s_invp[c];
        }
#pragma unroll
        for (int q = 0; q < 4; q++) {
          float4 v; v.x=outv[4*q]; v.y=outv[4*q+1]; v.z=outv[4*q+2]; v.w=outv[4*q+3];
          *(float4*)(c_ws + ((size_t)(bn*255 + k))*1024 + r*32 + c16 + 4*q) = v;
        }
#pragma unroll
        for (int i = 0; i < 16; i++) sCT[(c16+i)*36 + r] = outv[i];
      }
      __syncthreads();
#pragma unroll
      for (int q = 0; q < 4; q++) { jq[q] = jn[q]; pq[q] = pn[q]; }
      hq = hn;
    }
  } else {
    // ================== chol chain: M_k = Jdb_k - Ll Ll^T; L, Ll, x ==================
    __shared__ __align__(16) float sLl[32*36];
    __shared__ __align__(16) float sLT[32*36];   // LT[j][p] = L[p][j]
    __shared__ __align__(16) float s_x[32];
    __shared__ __align__(16) float s_invd[32];   // 1/L[j][j]
    __shared__ __align__(16) float s_invr[32];   // 1/(L[j][j]+eps_bs)
    const float* nb = noise + (size_t)bn * 8192;

    float4 jq[4], pq[4]; float nq;
#pragma unroll
    for (int q = 0; q < 4; q++) jq[q] = *(const float4*)(Jb + r*32 + c16 + 4*q);
#pragma unroll
    for (int q = 0; q < 4; q++) pq[q] = *(const float4*)(Pb + r*32 + c16 + 4*q);
    nq = nb[r];

    for (int k = 0; k < 256; k++) {
      float4 jn[4], pn[4]; float nn = 0.f;
      if (k < 255) {
#pragma unroll
        for (int q = 0; q < 4; q++)
          jn[q] = *(const float4*)(Jb + (size_t)(k+1)*1024 + r*32 + c16 + 4*q);
        nn = nb[(k+1)*32 + r];
        if (k + 1 < 255) {
#pragma unroll
          for (int q = 0; q < 4; q++)
            pn[q] = *(const float4*)(Pb + (size_t)(k+1)*1024 + r*32 + c16 + 4*q);
        }
      }
      // xr = z_k - Ll_prev^T x_prev
      float xr_r = nq;
      if (k >= 1) {
        float a = 0.f;
#pragma unroll
        for (int j = 0; j < 32; j++) a += sLl[36*j + r] * s_x[j];
        xr_r -= a;
      }
      // M build
      float m[16];
#pragma unroll
      for (int i = 0; i < 16; i++) m[i] = F4C(jq[i >> 2], i & 3);
      if (k >= 1) {
        float lrow[32];
#pragma unroll
        for (int q = 0; q < 8; q++) {
          const float4 v = *(const float4*)(&sLl[36*r + 4*q]);
          lrow[4*q]=v.x; lrow[4*q+1]=v.y; lrow[4*q+2]=v.z; lrow[4*q+3]=v.w;
        }
#pragma unroll
        for (int i = 0; i < 16; i++) {
          const int c = c16 + i;
          float acc = 0.f;
#pragma unroll
          for (int q = 0; q < 8; q++) {
            const float4 v = *(const float4*)(&sLl[36*c + 4*q]);
            acc += lrow[4*q]*v.x + lrow[4*q+1]*v.y + lrow[4*q+2]*v.z + lrow[4*q+3]*v.w;
          }
          m[i] -= acc;
        }
      }
      // cholesky, in registers, column broadcast via bpermute
#pragma unroll
      for (int j = 0; j < 32; j++) {
        const int jl = j & 15, jh = j >> 4;
        const float colv = m[jl];                    // snapshot of column-j register slot
        const float dpiv = __shfl(colv, 2*j + jh);
        const float sq = sqrtf(dpiv);
        const float inv = __builtin_amdgcn_rcpf(sq);
        const float fr = __shfl(colv, 2*r + jh);     // M[r][j]
        if (h2 == 0 && r >= j) sLT[36*j + r] = (r == j) ? sq : fr*inv;
        if (lane == 0) { s_invd[j] = inv; s_invr[j] = __builtin_amdgcn_rcpf(sq + EPS_BS); }
        const float s2 = (r > j) ? fr*inv*inv : 0.f;
#pragma unroll
        for (int i = 0; i < 16; i++) {
          const float cc = __shfl(colv, 2*(c16+i) + jh);   // M[c][j]
          m[i] -= s2 * cc;
        }
      }
      __syncthreads();
      // Ll row r: solve L^T y = -P[r,:]^T  (backward), y[j] = Ll[r][j]
      if (k < 255) {
        float invd_[32];
#pragma unroll
        for (int q = 0; q < 8; q++) {
          const float4 v = *(const float4*)(&s_invd[4*q]);
          invd_[4*q]=v.x; invd_[4*q+1]=v.y; invd_[4*q+2]=v.z; invd_[4*q+3]=v.w;
        }
        float y[32];
#pragma unroll
        for (int j = 31; j >= 0; j--) {
          const float own = F4C(pq[(j & 15) >> 2], j & 3);
          const float oth = __shfl_xor(own, 1);
          const float pv = ((j >> 4) == h2) ? own : oth;   // P[r][j]
          float ssum = 0.f;
#pragma unroll
          for (int qq = (j + 1) >> 2; qq < 8; qq++) {
            const float4 v = *(const float4*)(&sLT[36*j + 4*qq]);
#pragma unroll
            for (int e2 = 0; e2 < 4; e2++) {
              const int p = 4*qq + e2;
              if (p > j) ssum += F4C(v, e2) * y[p];
            }
          }
          y[j] = (-pv - ssum) * invd_[j];
        }
        if (h2 == 0) {
#pragma unroll
          for (int q = 0; q < 8; q++) {
            float4 v; v.x=y[4*q]; v.y=y[4*q+1]; v.z=y[4*q+2]; v.w=y[4*q+3];
            *(float4*)(&sLl[36*r + 4*q]) = v;
          }
        }
      }
      // x back-substitution: (L+eps)^T x = xr
      {
        float lc[32], ir_[32];
#pragma unroll
        for (int q = 0; q < 8; q++) {
          const float4 v = *(const float4*)(&sLT[36*r + 4*q]);
          lc[4*q]=v.x; lc[4*q+1]=v.y; lc[4*q+2]=v.z; lc[4*q+3]=v.w;
          const float4 w = *(const float4*)(&s_invr[4*q]);
          ir_[4*q]=w.x; ir_[4*q+1]=w.y; ir_[4*q+2]=w.z; ir_[4*q+3]=w.w;
        }
        float xp = xr_r;
        float myx = 0.f;
#pragma unroll
        for (int j = 31; j >= 0; j--) {
          const float xj = __shfl(xp * ir_[j], 2*j);
          if (j == r) myx = xj;
          if (r < j) xp -= lc[j] * xj;
        }
        if (h2 == 0) {
          s_x[r] = myx;
          x_ws[((size_t)(bn*256 + k))*32 + r] = myx;
        }
      }
      __syncthreads();
#pragma unroll
      for (int q = 0; q < 4; q++) { jq[q] = jn[q]; pq[q] = pn[q]; }
      nq = nn;
    }
  }
}

// ---------------- Fallback (validated R2): per-sample sequential chain ----------------
__global__ __launch_bounds__(256) void fwd_kernel_fb(const float* __restrict__ z,
                                                  const float* __restrict__ A_base,
                                                  const float* __restrict__ b_base,
                                                  const float* __restrict__ Q_sqrt,
                                                  const float* __restrict__ noise,
                                                  const float* __restrict__ Ris,
                                                  const float* __restrict__ Rm,
                                                  float* __restrict__ c_ws,
                                                  float* __restrict__ d_ws,
                                                  float* __restrict__ x_ws) {
  const int bn = blockIdx.x;
  const int tid = threadIdx.x;
  const int r  = tid >> 3;
  const int g  = tid & 7;
  const int c0 = g * 4;

  __shared__ float sAs[32*LD], sQs[32*LD], sM[32*LD], sL[32*LD];
  __shared__ float sQis[2][32*LD], sP[2][32*LD], sLl[2][32*LD], sC[2][32*LD];
  __shared__ float sW[32*WLD];
  __shared__ float sGJ[32*GLD];
  __shared__ float sz[2048];
  __shared__ float s_bs[32], s_rhs[32], s_d[32], s_x[32], s_xr[32];
  __shared__ float s_inv[32], s_invr[32], s_invp[32], s_hc[2][32];

  {
    const float* zn = z + (size_t)bn * 2048;
    const int e = tid * 8;
    float4 v0 = *(const float4*)(zn + e);
    float4 v1 = *(const float4*)(zn + e + 4);
    *(float4*)(sz + e)     = v0;
    *(float4*)(sz + e + 4) = v1;
  }
  __syncthreads();

  for (int k = 0; k < 256; k++) {
    const int cur = k & 1, prv = cur ^ 1;
    const bool have_cur = (k < 255);
    const bool have_prv = (k >= 1);

    if (have_cur) {
      float a0=0.f,a1=0.f,a2=0.f,a3=0.f,q0=0.f,q1=0.f,q2=0.f,q3=0.f;
#pragma unroll
      for (int kq = 0; kq < 8; kq++) {
        const float zq = sz[k*8 + kq];
        const float4 av = *(const float4*)(A_base + kq*1024 + r*32 + c0);
        const float4 qv = *(const float4*)(Q_sqrt + kq*1024 + r*32 + c0);
        a0 += zq*av.x; a1 += zq*av.y; a2 += zq*av.z; a3 += zq*av.w;
        q0 += zq*qv.x; q1 += zq*qv.y; q2 += zq*qv.z; q3 += zq*qv.w;
      }
      sAs[IDX(r,c0+0)]=a0; sAs[IDX(r,c0+1)]=a1; sAs[IDX(r,c0+2)]=a2; sAs[IDX(r,c0+3)]=a3;
      sQs[IDX(r,c0+0)]=q0; sQs[IDX(r,c0+1)]=q1; sQs[IDX(r,c0+2)]=q2; sQs[IDX(r,c0+3)]=q3;
      if (tid < 32) {
        float b = 0.f;
#pragma unroll
        for (int kq = 0; kq < 8; kq++) b += sz[k*8+kq] * b_base[kq*32 + tid];
        s_bs[tid] = b;
      }
    }
    __syncthreads();

    if (have_cur) {
      float a0=0.f,a1=0.f,a2=0.f,a3=0.f;
#pragma unroll
      for (int p = 0; p < 32; p++) {
        const float qr = sQs[IDX(r,p)];
        a0 += qr * sQs[IDX(c0+0,p)];
        a1 += qr * sQs[IDX(c0+1,p)];
        a2 += qr * sQs[IDX(c0+2,p)];
        a3 += qr * sQs[IDX(c0+3,p)];
      }
      sQis[cur][IDX(r,c0+0)]=a0; sQis[cur][IDX(r,c0+1)]=a1;
      sQis[cur][IDX(r,c0+2)]=a2; sQis[cur][IDX(r,c0+3)]=a3;
    }
    __syncthreads();

    if (have_cur) {
      float a0=0.f,a1=0.f,a2=0.f,a3=0.f;
#pragma unroll
      for (int p = 0; p < 32; p++) {
        const float qr = sQis[cur][IDX(r,p)];
        a0 += qr * sAs[IDX(p,c0+0)];
        a1 += qr * sAs[IDX(p,c0+1)];
        a2 += qr * sAs[IDX(p,c0+2)];
        a3 += qr * sAs[IDX(p,c0+3)];
      }
      sP[cur][IDX(r,c0+0)]=a0; sP[cur][IDX(r,c0+1)]=a1;
      sP[cur][IDX(r,c0+2)]=a2; sP[cur][IDX(r,c0+3)]=a3;
    }
    __syncthreads();

    {
      const float4 rv = *(const float4*)(Ris + (size_t)k*1024 + r*32 + c0);
      float b0 = rv.x, b1 = rv.y, b2 = rv.z, b3 = rv.w;
      if (r == c0+0) b0 += EPS_TRI;
      else if (r == c0+1) b1 += EPS_TRI;
      else if (r == c0+2) b2 += EPS_TRI;
      else if (r == c0+3) b3 += EPS_TRI;
      if (have_cur) {
#pragma unroll
        for (int p = 0; p < 32; p++) {
          const float ar = sAs[IDX(p,r)];
          b0 += ar * sP[cur][IDX(p,c0+0)];
          b1 += ar * sP[cur][IDX(p,c0+1)];
          b2 += ar * sP[cur][IDX(p,c0+2)];
          b3 += ar * sP[cur][IDX(p,c0+3)];
        }
      }
      float m0=b0, m1=b1, m2=b2, m3=b3;
      float j0=b0, j1=b1, j2=b2, j3=b3;
      if (have_prv) {
        const float q0 = sQis[prv][IDX(r,c0+0)];
        const float q1 = sQis[prv][IDX(r,c0+1)];
        const float q2 = sQis[prv][IDX(r,c0+2)];
        const float q3 = sQis[prv][IDX(r,c0+3)];
        m0 += q0; m1 += q1; m2 += q2; m3 += q3;
        j0 += q0; j1 += q1; j2 += q2; j3 += q3;
#pragma unroll
        for (int p = 0; p < 32; p++) {
          const float lr = sLl[prv][IDX(r,p)];
          m0 -= lr * sLl[prv][IDX(c0+0,p)];
          m1 -= lr * sLl[prv][IDX(c0+1,p)];
          m2 -= lr * sLl[prv][IDX(c0+2,p)];
          m3 -= lr * sLl[prv][IDX(c0+3,p)];
          const float pr = sP[prv][IDX(r,p)];
          j0 += pr * sC[prv][IDX(p,c0+0)];
          j1 += pr * sC[prv][IDX(p,c0+1)];
          j2 += pr * sC[prv][IDX(p,c0+2)];
          j3 += pr * sC[prv][IDX(p,c0+3)];
        }
      }
      sM[IDX(r,c0+0)]=m0; sM[IDX(r,c0+1)]=m1; sM[IDX(r,c0+2)]=m2; sM[IDX(r,c0+3)]=m3;
      sGJ[GIDX(r,c0+0)]=j0; sGJ[GIDX(r,c0+1)]=j1; sGJ[GIDX(r,c0+2)]=j2; sGJ[GIDX(r,c0+3)]=j3;
      sGJ[GIDX(r,32+c0+0)] = (r == c0+0) ? 1.f : 0.f;
      sGJ[GIDX(r,32+c0+1)] = (r == c0+1) ? 1.f : 0.f;
      sGJ[GIDX(r,32+c0+2)] = (r == c0+2) ? 1.f : 0.f;
      sGJ[GIDX(r,32+c0+3)] = (r == c0+3) ? 1.f : 0.f;

      if (tid < 32) {
        const int i = tid;
        float h = Rm[k*32 + i];
        if (have_cur) {
          float a = 0.f;
#pragma unroll
          for (int j = 0; j < 32; j++) a += sP[cur][IDX(i,j)] * s_bs[j];
          h -= a;
        }
        if (have_prv) h += s_hc[prv][i];
        float rr2 = h;
        if (have_prv) {
          float a = 0.f;
#pragma unroll
          for (int j = 0; j < 32; j++) a += sP[prv][IDX(i,j)] * s_d[j];
          rr2 += a;
        }
        s_rhs[i] = rr2;
      } else if (tid < 64) {
        const int i = tid - 32;
        if (have_cur) {
          float a = 0.f;
#pragma unroll
          for (int j = 0; j < 32; j++) a += sQis[cur][IDX(i,j)] * s_bs[j];
          s_hc[cur][i] = a;
        }
      } else if (tid < 96) {
        const int i = tid - 64;
        float xr = noise[(size_t)bn*8192 + k*32 + i];
        if (have_prv) {
          float a = 0.f;
#pragma unroll
          for (int j = 0; j < 32; j++) a += sLl[prv][IDX(j,i)] * s_x[j];
          xr -= a;
        }
        s_xr[i] = xr;
      }
    }
    __syncthreads();

    for (int j = 0; j < 32; j++) {
      {
        const float dj = sM[IDX(j,j)];
        const float sq = sqrtf(dj);
        const float inv = 1.0f / sq;
        const float mrj = sM[IDX(r,j)] * inv;
        if (g == 0 && r >= j) sL[IDX(r,j)] = (r == j) ? sq : mrj;
        if (r > j) {
#pragma unroll
          for (int i2 = 0; i2 < 4; i2++) {
            const int c = c0 + i2;
            if (c > j && c <= r) sM[IDX(r,c)] -= mrj * (sM[IDX(c,j)] * inv);
          }
        }
      }
      {
        const float pj = sGJ[GIDX(j,j)];
        const float ip = 1.0f / pj;
        if (r == j && g == 0) s_invp[j] = ip;
        if (r != j) {
          const float f = sGJ[GIDX(r,j)] * ip;
#pragma unroll
          for (int i2 = 0; i2 < 4; i2++) {
            const int c = c0 + i2;
            if (c > j) sGJ[GIDX(r,c)] -= f * sGJ[GIDX(j,c)];
          }
#pragma unroll
          for (int i2 = 0; i2 < 4; i2++) {
            const int c = 32 + c0 + i2;
            sGJ[GIDX(r,c)] -= f * sGJ[GIDX(j,c)];
          }
        }
      }
      __syncthreads();
    }

    if (tid < 32) {
      const float l = sL[IDX(tid,tid)];
      s_inv[tid]  = 1.0f / l;
      s_invr[tid] = 1.0f / (l + EPS_BS);
    }
#pragma unroll
    for (int i2 = 0; i2 < 4; i2++) sW[WIDX(r,c0+i2)] = 0.f;
    __syncthreads();

    {
      const int col = r;
      if (g == 0) sW[WIDX(col,col)] = s_inv[col];
      for (int i = 1; i < 32; i++) {
        float t = 0.f;
        for (int p = g; p < i; p += 8) t += sL[IDX(i,p)] * sW[WIDX(p,col)];
        t += __shfl_xor(t, 1);
        t += __shfl_xor(t, 2);
        t += __shfl_xor(t, 4);
        if (g == 0 && i > col) sW[WIDX(i,col)] = -t * s_inv[i];
      }
    }
    __syncthreads();

    if (have_cur) {
      float l0=0.f,l1=0.f,l2=0.f,l3=0.f;
      float v0=0.f,v1=0.f,v2=0.f,v3=0.f;
#pragma unroll
      for (int p = 0; p < 32; p++) {
        const float pr = sP[cur][IDX(r,p)];
        l0 += pr * sW[WIDX(p,c0+0)];
        l1 += pr * sW[WIDX(p,c0+1)];
        l2 += pr * sW[WIDX(p,c0+2)];
        l3 += pr * sW[WIDX(p,c0+3)];
        v0 += pr * sGJ[GIDX(c0+0,32+p)];
        v1 += pr * sGJ[GIDX(c0+1,32+p)];
        v2 += pr * sGJ[GIDX(c0+2,32+p)];
        v3 += pr * sGJ[GIDX(c0+3,32+p)];
      }
      sLl[cur][IDX(r,c0+0)]=-l0; sLl[cur][IDX(r,c0+1)]=-l1;
      sLl[cur][IDX(r,c0+2)]=-l2; sLl[cur][IDX(r,c0+3)]=-l3;
      v0 *= -s_invp[c0+0]; v1 *= -s_invp[c0+1];
      v2 *= -s_invp[c0+2]; v3 *= -s_invp[c0+3];
      sC[cur][IDX(r,c0+0)]=v0; sC[cur][IDX(r,c0+1)]=v1;
      sC[cur][IDX(r,c0+2)]=v2; sC[cur][IDX(r,c0+3)]=v3;
      float4 cv; cv.x=v0; cv.y=v1; cv.z=v2; cv.w=v3;
      *(float4*)(c_ws + ((size_t)(bn*255 + k))*1024 + r*32 + c0) = cv;
    }
    if (tid < 32) {
      float acc = 0.f;
#pragma unroll
      for (int j = 0; j < 32; j++) acc += sGJ[GIDX(tid,32+j)] * s_rhs[j];
      acc *= s_invp[tid];
      s_d[tid] = acc;
      d_ws[((size_t)(bn*256 + k))*32 + tid] = acc;
    } else if (tid >= 64 && tid < 96) {
      const int i = tid - 64;
      float xr = s_xr[i];
      float xv = 0.f;
      for (int j = 31; j >= 0; j--) {
        const float t = __shfl(xr, j, 32) * s_invr[j];
        if (i == j) xv = t;
        else if (i < j) xr -= sL[IDX(j,i)] * t;
      }
      s_x[i] = xv;
      x_ws[((size_t)(bn*256 + k))*32 + i] = xv;
    }
    __syncthreads();
  }
}

// ---------------- Phase 4: backward mu scan + output = x + mu ----------------
__global__ __launch_bounds__(256) void bwd_kernel(const float* __restrict__ c_ws,
                                                  const float* __restrict__ d_ws,
                                                  const float* __restrict__ x_ws,
                                                  float* __restrict__ out) {
  const int bn = blockIdx.x;
  const int tid = threadIdx.x;
  const int i = tid >> 3, g = tid & 7;
  __shared__ float s_mu[32];
  if (tid < 32) {
    const float mu = d_ws[((size_t)(bn*256 + 255))*32 + tid];
    s_mu[tid] = mu;
    out[((size_t)(bn*256 + 255))*32 + tid] =
        x_ws[((size_t)(bn*256 + 255))*32 + tid] + mu;
  }
  __syncthreads();
  float4 cv = *(const float4*)(c_ws + ((size_t)(bn*255 + 254))*1024 + i*32 + g*4);
  for (int k = 254; k >= 0; k--) {
    float4 cnext = make_float4(0.f, 0.f, 0.f, 0.f);
    if (k > 0)
      cnext = *(const float4*)(c_ws + ((size_t)(bn*255 + k - 1))*1024 + i*32 + g*4);
    float part = cv.x * s_mu[g*4+0] + cv.y * s_mu[g*4+1]
               + cv.z * s_mu[g*4+2] + cv.w * s_mu[g*4+3];
    part += __shfl_xor(part, 1);
    part += __shfl_xor(part, 2);
    part += __shfl_xor(part, 4);
    float dv = 0.f, xv = 0.f;
    if (g == 0) {
      dv = d_ws[((size_t)(bn*256 + k))*32 + i];
      xv = x_ws[((size_t)(bn*256 + k))*32 + i];
    }
    __syncthreads();
    if (g == 0) {
      const float mu = dv - part;
      s_mu[i] = mu;
      out[((size_t)(bn*256 + k))*32 + i] = xv + mu;
    }
    __syncthreads();
    cv = cnext;
  }
}

extern "C" void kernel_launch(void* const* d_in, const int* in_sizes, int n_in,
                              void* d_out, int out_size, void* d_ws, size_t ws_size,
                              hipStream_t stream) {
  const float* z      = (const float*)d_in[0];   // (64,256,8)
  const float* A_base = (const float*)d_in[1];   // (8,32,32)
  const float* b_base = (const float*)d_in[2];   // (8,32)
  const float* Q_sqrt = (const float*)d_in[3];   // (8,32,32)
  const float* ms     = (const float*)d_in[4];   // (256,32)
  const float* Ri     = (const float*)d_in[5];   // (256,32,32)
  const float* noise  = (const float*)d_in[6];   // (64,8192)
  float* out = (float*)d_out;

  float* ws = (float*)d_ws;
  const size_t SZ_C = (size_t)64*255*1024;
  const size_t SZ_J = (size_t)64*256*1024;
  const size_t SZ_V = (size_t)64*256*32;
  const size_t need_new = (SZ_C*2 + SZ_J + SZ_V*3 + (size_t)256*1024 + 256*32) * 4;

  if (ws_size >= need_new) {
    float* c_ws  = ws;
    float* Jdb   = c_ws + SZ_C;
    float* Pm    = Jdb + SZ_J;
    float* hbuf  = Pm + SZ_C;
    float* d_vec = hbuf + SZ_V;
    float* x_vec = d_vec + SZ_V;
    float* Ris   = x_vec + SZ_V;
    float* Rm    = Ris + (size_t)256*1024;

    ris_kernel<<<256, 256, 0, stream>>>(Ri, ms, Ris, Rm);
    pre_kernel<<<16384, 256, 0, stream>>>(z, A_base, b_base, Q_sqrt, Ris, Rm, Jdb, Pm, hbuf);
    chain_kernel<<<128, 64, 0, stream>>>(Jdb, Pm, hbuf, noise, c_ws, d_vec, x_vec);
    bwd_kernel<<<64, 256, 0, stream>>>(c_ws, d_vec, x_vec, out);
  } else {
    float* c_ws  = ws;
    float* d_vec = c_ws + SZ_C;
    float* x_vec = d_vec + SZ_V;
    float* Ris   = x_vec + SZ_V;
    float* Rm    = Ris + (size_t)256*1024;

    ris_kernel<<<256, 256, 0, stream>>>(Ri, ms, Ris, Rm);
    fwd_kernel_fb<<<64, 256, 0, stream>>>(z, A_base, b_base, Q_sqrt, noise, Ris, Rm,
                                          c_ws, d_vec, x_vec);
    bwd_kernel<<<64, 256, 0, stream>>>(c_ws, d_vec, x_vec, out);
  }
}